// Round 1
// baseline (547.594 us; speedup 1.0000x reference)
//
#include <hip/hip_runtime.h>
#include <hip/hip_bf16.h>

// Problem constants (fixed by reference setup_inputs)
#define BB 4
#define SS 4096
#define DD 1024
#define HH 16
#define HD 64
#define MM (BB * SS)      // 16384
#define KK DD             // 1024
#define NN DD             // 1024

typedef __bf16 bf16x8 __attribute__((ext_vector_type(8)));
typedef float f32x4 __attribute__((ext_vector_type(4)));

// ---------------------------------------------------------------------------
// fp32 -> bf16 conversion (vectorized, n must be multiple of 4)
// ---------------------------------------------------------------------------
__global__ __launch_bounds__(256)
void cvt_f32_bf16(const float* __restrict__ in, __hip_bfloat16* __restrict__ out, int n4) {
    int i = blockIdx.x * 256 + threadIdx.x;
    if (i >= n4) return;
    float4 v = ((const float4*)in)[i];
    union { __hip_bfloat16 h[4]; uint2 u; } r;
    r.h[0] = __float2bfloat16(v.x);
    r.h[1] = __float2bfloat16(v.y);
    r.h[2] = __float2bfloat16(v.z);
    r.h[3] = __float2bfloat16(v.w);
    ((uint2*)out)[i] = r.u;
}

// ---------------------------------------------------------------------------
// GEMM: C[M,N] = epilogue( X[M,K] @ W[N,K]^T )
// EPI: 0 = store bf16, 1 = elu(x)+1 then bf16, 2 = store fp32
// 128x128 tile / block, 4 waves, each wave 64x64 via 4x4 frags of 16x16x32.
// ---------------------------------------------------------------------------
template<int EPI>
__global__ __launch_bounds__(256)
void gemm_bt(const __hip_bfloat16* __restrict__ X,
             const __hip_bfloat16* __restrict__ W,
             __hip_bfloat16* __restrict__ Cb,
             float* __restrict__ Cf,
             int M, int N, int K)
{
    __shared__ __align__(16) __hip_bfloat16 sA[128][32];
    __shared__ __align__(16) __hip_bfloat16 sB[128][32];

    const int t    = threadIdx.x;
    const int lane = t & 63;
    const int wv   = t >> 6;           // wave id 0..3
    const int wm   = (wv >> 1) * 64;   // wave row offset within tile
    const int wn   = (wv & 1) * 64;    // wave col offset within tile
    const int m0   = blockIdx.y * 128;
    const int n0   = blockIdx.x * 128;

    const int lrow = lane & 15;        // A: m-index, B: n-index, C: col
    const int lq   = lane >> 4;        // quad: k = lq*8 + j; C: row = lq*4 + reg

    f32x4 acc[4][4];
    #pragma unroll
    for (int i = 0; i < 4; i++)
        #pragma unroll
        for (int j = 0; j < 4; j++)
            acc[i][j] = (f32x4){0.f, 0.f, 0.f, 0.f};

    for (int kk = 0; kk < K; kk += 32) {
        // Stage 128x32 bf16 of X and W: 2 x 16B per thread per matrix.
        #pragma unroll
        for (int i = 0; i < 2; i++) {
            int li = (t + i * 256) * 8;    // element index in tile
            int r  = li >> 5;              // /32
            int c  = li & 31;
            *(float4*)(&sA[r][c]) = *(const float4*)(&X[(size_t)(m0 + r) * K + kk + c]);
            *(float4*)(&sB[r][c]) = *(const float4*)(&W[(size_t)(n0 + r) * K + kk + c]);
        }
        __syncthreads();

        bf16x8 af[4], bf[4];
        #pragma unroll
        for (int i = 0; i < 4; i++) {
            af[i] = *(const bf16x8*)(&sA[wm + i * 16 + lrow][lq * 8]);
            bf[i] = *(const bf16x8*)(&sB[wn + i * 16 + lrow][lq * 8]);
        }
        #pragma unroll
        for (int i = 0; i < 4; i++)
            #pragma unroll
            for (int j = 0; j < 4; j++)
                acc[i][j] = __builtin_amdgcn_mfma_f32_16x16x32_bf16(af[i], bf[j], acc[i][j], 0, 0, 0);
        __syncthreads();
    }

    // Epilogue. C/D layout: col = lane&15, row = (lane>>4)*4 + reg.
    #pragma unroll
    for (int i = 0; i < 4; i++) {
        #pragma unroll
        for (int j = 0; j < 4; j++) {
            #pragma unroll
            for (int r = 0; r < 4; r++) {
                int row = m0 + wm + i * 16 + lq * 4 + r;
                int col = n0 + wn + j * 16 + lrow;
                float v = acc[i][j][r];
                if (EPI == 1) v = (v > 0.f) ? (v + 1.f) : __expf(v);  // elu(v)+1
                if (EPI == 2) {
                    Cf[(size_t)row * N + col] = v;
                } else {
                    Cb[(size_t)row * N + col] = __float2bfloat16(v);
                }
            }
        }
    }
}

// ---------------------------------------------------------------------------
// KV[b,h] = sum_s k[b,s,h,:] (outer) v[b,s,h,:]   (64x64 fp32, atomic accum)
// KS[b,h] = sum_s k[b,s,h,:]
// grid (B*H, SPLIT), block 256. Each thread owns a 4x4 patch of KV.
// ---------------------------------------------------------------------------
#define KV_SPLIT 16
__global__ __launch_bounds__(256)
void kv_kernel(const __hip_bfloat16* __restrict__ Kt,
               const __hip_bfloat16* __restrict__ Vt,
               float* __restrict__ KV, float* __restrict__ KS)
{
    const int bh = blockIdx.x;
    const int b  = bh >> 4;
    const int h  = bh & 15;
    const int sp = blockIdx.y;
    const int schunk = SS / KV_SPLIT;  // 256
    const int s0 = sp * schunk;
    const int t  = threadIdx.x;
    const int de = t >> 4;  // d block (0..15) -> d = de*4..de*4+3
    const int ee = t & 15;  // e block (0..15)

    __shared__ float sk[8][64];
    __shared__ float sv[8][64];

    float acc[4][4] = {};
    float ks[4] = {};

    const __hip_bfloat16* kp = Kt + (size_t)b * SS * DD + (size_t)h * HD;
    const __hip_bfloat16* vp = Vt + (size_t)b * SS * DD + (size_t)h * HD;

    for (int s = s0; s < s0 + schunk; s += 8) {
        __syncthreads();
        {
            int idx = t * 2;        // 0..510, covers 8x64
            int r = idx >> 6, c = idx & 63;
            __hip_bfloat162 k2 = *(const __hip_bfloat162*)(kp + (size_t)(s + r) * DD + c);
            __hip_bfloat162 v2 = *(const __hip_bfloat162*)(vp + (size_t)(s + r) * DD + c);
            sk[r][c]     = __bfloat162float(k2.x);
            sk[r][c + 1] = __bfloat162float(k2.y);
            sv[r][c]     = __bfloat162float(v2.x);
            sv[r][c + 1] = __bfloat162float(v2.y);
        }
        __syncthreads();
        #pragma unroll
        for (int r = 0; r < 8; r++) {
            float kd[4], ve[4];
            #pragma unroll
            for (int i = 0; i < 4; i++) { kd[i] = sk[r][de * 4 + i]; ve[i] = sv[r][ee * 4 + i]; }
            #pragma unroll
            for (int i = 0; i < 4; i++)
                #pragma unroll
                for (int j = 0; j < 4; j++)
                    acc[i][j] += kd[i] * ve[j];
            if (ee == 0) {
                #pragma unroll
                for (int i = 0; i < 4; i++) ks[i] += kd[i];
            }
        }
    }

    float* kvp = KV + (size_t)bh * HD * HD;
    #pragma unroll
    for (int i = 0; i < 4; i++)
        #pragma unroll
        for (int j = 0; j < 4; j++)
            atomicAdd(&kvp[(de * 4 + i) * HD + ee * 4 + j], acc[i][j]);
    if (ee == 0) {
        #pragma unroll
        for (int i = 0; i < 4; i++) atomicAdd(&KS[bh * HD + de * 4 + i], ks[i]);
    }
}

// ---------------------------------------------------------------------------
// out[b,s,h,:] = (q[b,s,h,:] @ KV[b,h]) / (q . KS[b,h] + eps), stored bf16
// grid (B*H, S/256), block 256 (one s per thread).
// ---------------------------------------------------------------------------
__global__ __launch_bounds__(256)
void attn_kernel(const __hip_bfloat16* __restrict__ Q,
                 const float* __restrict__ KV,
                 const float* __restrict__ KS,
                 __hip_bfloat16* __restrict__ O)
{
    const int bh = blockIdx.x;
    const int b  = bh >> 4;
    const int h  = bh & 15;
    const int s  = blockIdx.y * 256 + threadIdx.x;

    __shared__ float skv[64][64];
    __shared__ float sks[64];
    const float* kvp = KV + (size_t)bh * 4096;
    for (int i = threadIdx.x; i < 4096; i += 256) skv[i >> 6][i & 63] = kvp[i];
    if (threadIdx.x < 64) sks[threadIdx.x] = KS[bh * 64 + threadIdx.x];
    __syncthreads();

    const __hip_bfloat16* qp = Q + ((size_t)b * SS + s) * DD + h * HD;
    float q[64];
    #pragma unroll
    for (int d = 0; d < 64; d += 8) {
        union { float4 f; __hip_bfloat16 h8[8]; } u;
        u.f = *(const float4*)(qp + d);
        #pragma unroll
        for (int j = 0; j < 8; j++) q[d + j] = __bfloat162float(u.h8[j]);
    }

    float z = 0.f;
    #pragma unroll
    for (int d = 0; d < 64; d++) z += q[d] * sks[d];
    const float scale = 1.f / (z + 1e-6f);

    __hip_bfloat16* op = O + ((size_t)b * SS + s) * DD + h * HD;
    #pragma unroll
    for (int half = 0; half < 2; half++) {
        float o[32];
        #pragma unroll
        for (int e = 0; e < 32; e++) o[e] = 0.f;
        for (int d = 0; d < 64; d++) {
            float qd = q[d];
            #pragma unroll
            for (int e = 0; e < 32; e += 4) {
                float4 kv = *(const float4*)(&skv[d][half * 32 + e]);
                o[e]     += qd * kv.x;
                o[e + 1] += qd * kv.y;
                o[e + 2] += qd * kv.z;
                o[e + 3] += qd * kv.w;
            }
        }
        #pragma unroll
        for (int e = 0; e < 32; e += 4) {
            union { __hip_bfloat16 h4[4]; uint2 u; } r;
            r.h4[0] = __float2bfloat16(o[e]     * scale);
            r.h4[1] = __float2bfloat16(o[e + 1] * scale);
            r.h4[2] = __float2bfloat16(o[e + 2] * scale);
            r.h4[3] = __float2bfloat16(o[e + 3] * scale);
            *(uint2*)(op + half * 32 + e) = r.u;
        }
    }
}

// ---------------------------------------------------------------------------
// launch
// ---------------------------------------------------------------------------
extern "C" void kernel_launch(void* const* d_in, const int* in_sizes, int n_in,
                              void* d_out, int out_size, void* d_ws, size_t ws_size,
                              hipStream_t stream) {
    const float* x  = (const float*)d_in[0];
    const float* Wq = (const float*)d_in[1];
    const float* Wk = (const float*)d_in[2];
    const float* Wv = (const float*)d_in[3];
    const float* Wo = (const float*)d_in[4];
    float* out = (float*)d_out;

    // workspace layout (bytes)
    char* ws = (char*)d_ws;
    const size_t XB_BYTES = (size_t)MM * KK * 2;   // 32MB
    const size_t WB_BYTES = (size_t)NN * KK * 2;   // 2MB
    __hip_bfloat16* xb  = (__hip_bfloat16*)(ws);
    __hip_bfloat16* wqb = (__hip_bfloat16*)(ws + XB_BYTES);
    __hip_bfloat16* wkb = (__hip_bfloat16*)(ws + XB_BYTES + WB_BYTES);
    __hip_bfloat16* wvb = (__hip_bfloat16*)(ws + XB_BYTES + 2 * WB_BYTES);
    __hip_bfloat16* wob = (__hip_bfloat16*)(ws + XB_BYTES + 3 * WB_BYTES);
    __hip_bfloat16* qb  = (__hip_bfloat16*)(ws + XB_BYTES + 4 * WB_BYTES);
    __hip_bfloat16* kb  = (__hip_bfloat16*)(ws + 2 * XB_BYTES + 4 * WB_BYTES);
    __hip_bfloat16* vb  = (__hip_bfloat16*)(ws + 3 * XB_BYTES + 4 * WB_BYTES);
    float* KV = (float*)(ws + 4 * XB_BYTES + 4 * WB_BYTES);          // 1MB
    float* KS = (float*)(ws + 4 * XB_BYTES + 4 * WB_BYTES + 1048576); // 16KB
    __hip_bfloat16* ab = xb;  // attn output reuses x's bf16 buffer (x dead by then)

    const int XN = MM * KK;   // 16777216
    const int WN = NN * KK;   // 1048576

    // 1. convert inputs to bf16
    cvt_f32_bf16<<<XN / 4 / 256, 256, 0, stream>>>(x,  xb,  XN / 4);
    cvt_f32_bf16<<<WN / 4 / 256, 256, 0, stream>>>(Wq, wqb, WN / 4);
    cvt_f32_bf16<<<WN / 4 / 256, 256, 0, stream>>>(Wk, wkb, WN / 4);
    cvt_f32_bf16<<<WN / 4 / 256, 256, 0, stream>>>(Wv, wvb, WN / 4);
    cvt_f32_bf16<<<WN / 4 / 256, 256, 0, stream>>>(Wo, wob, WN / 4);

    // 2. projections (elu+1 fused for q,k)
    dim3 ggrid(NN / 128, MM / 128);
    gemm_bt<1><<<ggrid, 256, 0, stream>>>(xb, wqb, qb, nullptr, MM, NN, KK);
    gemm_bt<1><<<ggrid, 256, 0, stream>>>(xb, wkb, kb, nullptr, MM, NN, KK);
    gemm_bt<0><<<ggrid, 256, 0, stream>>>(xb, wvb, vb, nullptr, MM, NN, KK);

    // 3. KV + k_sum (zero accumulators first; ws is poisoned each call)
    hipMemsetAsync(KV, 0, 1048576 + 16384, stream);
    kv_kernel<<<dim3(BB * HH, KV_SPLIT), 256, 0, stream>>>(kb, vb, KV, KS);

    // 4. attention output (normalized), bf16
    attn_kernel<<<dim3(BB * HH, SS / 256), 256, 0, stream>>>(qb, KV, KS, ab);

    // 5. final projection -> fp32 d_out
    gemm_bt<2><<<ggrid, 256, 0, stream>>>(ab, wob, nullptr, out, MM, NN, KK);
}

// Round 2
// 470.201 us; speedup vs baseline: 1.1646x; 1.1646x over previous
//
#include <hip/hip_runtime.h>
#include <hip/hip_bf16.h>

// Problem constants (fixed by reference setup_inputs)
#define BB 4
#define SS 4096
#define DD 1024
#define HH 16
#define HD 64
#define MM (BB * SS)      // 16384
#define KK DD             // 1024
#define NN DD             // 1024

typedef __bf16 bf16x8 __attribute__((ext_vector_type(8)));
typedef float f32x4 __attribute__((ext_vector_type(4)));

typedef __attribute__((address_space(3))) void lds_void_t;
typedef const __attribute__((address_space(1))) void glb_void_t;

// ---------------------------------------------------------------------------
// fp32 -> bf16 conversion (vectorized, n must be multiple of 4)
// ---------------------------------------------------------------------------
__global__ __launch_bounds__(256)
void cvt_f32_bf16(const float* __restrict__ in, __hip_bfloat16* __restrict__ out, int n4) {
    int i = blockIdx.x * 256 + threadIdx.x;
    if (i >= n4) return;
    float4 v = ((const float4*)in)[i];
    union { __hip_bfloat16 h[4]; uint2 u; } r;
    r.h[0] = __float2bfloat16(v.x);
    r.h[1] = __float2bfloat16(v.y);
    r.h[2] = __float2bfloat16(v.z);
    r.h[3] = __float2bfloat16(v.w);
    ((uint2*)out)[i] = r.u;
}

// ---------------------------------------------------------------------------
// GEMM: C[M,N] = epilogue( X[M,K] @ W[N,K]^T )   — m97 structure:
// 128x128 tile, 4 waves, 16x16x32 bf16 MFMA, global_load_lds width-16 staging.
// LDS tiles MUST be unpadded/contiguous in tid*16B order (global_load_lds
// writes wave-uniform base + lane*16).
// EPI: 0 = store bf16, 1 = elu(x)+1 then bf16, 2 = store fp32
// ---------------------------------------------------------------------------
template<int EPI>
__global__ __launch_bounds__(256)
void gemm_bt(const __hip_bfloat16* __restrict__ X,
             const __hip_bfloat16* __restrict__ W,
             __hip_bfloat16* __restrict__ Cb,
             float* __restrict__ Cf,
             int M, int N, int K)
{
    __shared__ __align__(16) __hip_bfloat16 sA[128][32];
    __shared__ __align__(16) __hip_bfloat16 sB[128][32];

    const int t    = threadIdx.x;
    const int lane = t & 63;
    const int wv   = t >> 6;           // wave id 0..3
    const int wm   = (wv >> 1) * 64;   // wave row offset within tile
    const int wn   = (wv & 1) * 64;    // wave col offset within tile
    const int m0   = blockIdx.y * 128;
    const int n0   = blockIdx.x * 128;

    const int lrow = lane & 15;        // A: m-index, B: n-index, C: col
    const int lq   = lane >> 4;        // quad: k = lq*8 + j; C: row = lq*4 + reg

    f32x4 acc[4][4];
    #pragma unroll
    for (int i = 0; i < 4; i++)
        #pragma unroll
        for (int j = 0; j < 4; j++)
            acc[i][j] = (f32x4){0.f, 0.f, 0.f, 0.f};

    for (int kk = 0; kk < K; kk += 32) {
        // Async global->LDS staging: 2 x 16B per thread per matrix.
        // LDS byte offset for element index (t+i*256)*8 is (t+i*256)*16:
        // exactly wave-uniform-base + lane*16 -> legal for global_load_lds.
        #pragma unroll
        for (int i = 0; i < 2; i++) {
            int li = (t + i * 256) * 8;    // element index in 128x32 tile
            int r  = li >> 5;              // /32
            int c  = li & 31;
            __builtin_amdgcn_global_load_lds(
                (glb_void_t*)&X[(size_t)(m0 + r) * K + kk + c],
                (lds_void_t*)&sA[r][c], 16, 0, 0);
            __builtin_amdgcn_global_load_lds(
                (glb_void_t*)&W[(size_t)(n0 + r) * K + kk + c],
                (lds_void_t*)&sB[r][c], 16, 0, 0);
        }
        __syncthreads();

        bf16x8 af[4], bfv[4];
        #pragma unroll
        for (int i = 0; i < 4; i++) {
            af[i]  = *(const bf16x8*)(&sA[wm + i * 16 + lrow][lq * 8]);
            bfv[i] = *(const bf16x8*)(&sB[wn + i * 16 + lrow][lq * 8]);
        }
        #pragma unroll
        for (int i = 0; i < 4; i++)
            #pragma unroll
            for (int j = 0; j < 4; j++)
                acc[i][j] = __builtin_amdgcn_mfma_f32_16x16x32_bf16(af[i], bfv[j], acc[i][j], 0, 0, 0);
        __syncthreads();
    }

    // Epilogue. C/D layout: col = lane&15, row = (lane>>4)*4 + reg.
    #pragma unroll
    for (int i = 0; i < 4; i++) {
        #pragma unroll
        for (int j = 0; j < 4; j++) {
            #pragma unroll
            for (int r = 0; r < 4; r++) {
                int row = m0 + wm + i * 16 + lq * 4 + r;
                int col = n0 + wn + j * 16 + lrow;
                float v = acc[i][j][r];
                if (EPI == 1) v = (v > 0.f) ? (v + 1.f) : __expf(v);  // elu(v)+1
                if (EPI == 2) {
                    Cf[(size_t)row * N + col] = v;
                } else {
                    Cb[(size_t)row * N + col] = __float2bfloat16(v);
                }
            }
        }
    }
}

// ---------------------------------------------------------------------------
// KV[b,h] = sum_s k[b,s,h,:] (outer) v[b,s,h,:]   (64x64 fp32, atomic accum)
// KS[b,h] = sum_s k[b,s,h,:]
// ---------------------------------------------------------------------------
#define KV_SPLIT 16
__global__ __launch_bounds__(256)
void kv_kernel(const __hip_bfloat16* __restrict__ Kt,
               const __hip_bfloat16* __restrict__ Vt,
               float* __restrict__ KV, float* __restrict__ KS)
{
    const int bh = blockIdx.x;
    const int b  = bh >> 4;
    const int h  = bh & 15;
    const int sp = blockIdx.y;
    const int schunk = SS / KV_SPLIT;  // 256
    const int s0 = sp * schunk;
    const int t  = threadIdx.x;
    const int de = t >> 4;  // d block (0..15) -> d = de*4..de*4+3
    const int ee = t & 15;  // e block (0..15)

    __shared__ float sk[8][64];
    __shared__ float sv[8][64];

    float acc[4][4] = {};
    float ks[4] = {};

    const __hip_bfloat16* kp = Kt + (size_t)b * SS * DD + (size_t)h * HD;
    const __hip_bfloat16* vp = Vt + (size_t)b * SS * DD + (size_t)h * HD;

    for (int s = s0; s < s0 + schunk; s += 8) {
        __syncthreads();
        {
            int idx = t * 2;        // 0..510, covers 8x64
            int r = idx >> 6, c = idx & 63;
            __hip_bfloat162 k2 = *(const __hip_bfloat162*)(kp + (size_t)(s + r) * DD + c);
            __hip_bfloat162 v2 = *(const __hip_bfloat162*)(vp + (size_t)(s + r) * DD + c);
            sk[r][c]     = __bfloat162float(k2.x);
            sk[r][c + 1] = __bfloat162float(k2.y);
            sv[r][c]     = __bfloat162float(v2.x);
            sv[r][c + 1] = __bfloat162float(v2.y);
        }
        __syncthreads();
        #pragma unroll
        for (int r = 0; r < 8; r++) {
            float kd[4], ve[4];
            #pragma unroll
            for (int i = 0; i < 4; i++) { kd[i] = sk[r][de * 4 + i]; ve[i] = sv[r][ee * 4 + i]; }
            #pragma unroll
            for (int i = 0; i < 4; i++)
                #pragma unroll
                for (int j = 0; j < 4; j++)
                    acc[i][j] += kd[i] * ve[j];
            if (ee == 0) {
                #pragma unroll
                for (int i = 0; i < 4; i++) ks[i] += kd[i];
            }
        }
    }

    float* kvp = KV + (size_t)bh * HD * HD;
    #pragma unroll
    for (int i = 0; i < 4; i++)
        #pragma unroll
        for (int j = 0; j < 4; j++)
            atomicAdd(&kvp[(de * 4 + i) * HD + ee * 4 + j], acc[i][j]);
    if (ee == 0) {
        #pragma unroll
        for (int i = 0; i < 4; i++) atomicAdd(&KS[bh * HD + de * 4 + i], ks[i]);
    }
}

// ---------------------------------------------------------------------------
// MFMA attention apply: out[b,s,h,:] = (q[b,s,h,:] @ KV[b,h]) / (q.KS + eps)
// Per block: one (b,h), 128 s-rows. M=128, N=64, K=64 via 16x16x32 MFMA.
// sQ/sKVt padded to 72 cols (144B row stride -> bank stride 4, only 2-way
// conflicts on frag reads, which are free).
// ---------------------------------------------------------------------------
__global__ __launch_bounds__(256)
void attn_mfma(const __hip_bfloat16* __restrict__ Q,
               const float* __restrict__ KV,
               const float* __restrict__ KS,
               __hip_bfloat16* __restrict__ O)
{
    const int bh = blockIdx.x;       // 0..63
    const int b  = bh >> 4;
    const int h  = bh & 15;
    const int s0 = blockIdx.y * 128;
    const int t  = threadIdx.x;
    const int lane = t & 63;
    const int wv = t >> 6;

    __shared__ __align__(16) __hip_bfloat16 sQ[128][72];
    __shared__ __align__(16) __hip_bfloat16 sKVt[64][72];   // [e][d] (transposed)
    __shared__ float sKS[64];
    __shared__ float sZ[128];                               // 1/(z+eps)

    // Load KV (fp32, [d][e] row-major) -> bf16 transposed into sKVt[e][d]
    {
        const float* kvp = KV + (size_t)bh * 4096;
        int base = t * 16;          // 16 consecutive idx share d
        int d  = base >> 6;
        int e0 = base & 63;
        #pragma unroll
        for (int i = 0; i < 16; i += 4) {
            float4 v = *(const float4*)(kvp + base + i);
            sKVt[e0 + i    ][d] = __float2bfloat16(v.x);
            sKVt[e0 + i + 1][d] = __float2bfloat16(v.y);
            sKVt[e0 + i + 2][d] = __float2bfloat16(v.z);
            sKVt[e0 + i + 3][d] = __float2bfloat16(v.w);
        }
        if (t < 64) sKS[t] = KS[bh * 64 + t];
    }
    // Load Q tile: rows s0..s0+127, cols h*64..h*64+63 (2 threads per row)
    {
        const __hip_bfloat16* qp = Q + ((size_t)b * SS + s0) * DD + h * HD;
        int r  = t >> 1;
        int c0 = (t & 1) * 32;
        #pragma unroll
        for (int i = 0; i < 32; i += 8)
            *(float4*)(&sQ[r][c0 + i]) = *(const float4*)(qp + (size_t)r * DD + c0 + i);
    }
    __syncthreads();

    // z per row (threads 0..127; wave-uniform branch for waves 0,1)
    if (t < 128) {
        float z = 0.f;
        #pragma unroll
        for (int d8 = 0; d8 < 64; d8 += 8) {
            bf16x8 qv = *(const bf16x8*)(&sQ[t][d8]);
            #pragma unroll
            for (int j = 0; j < 8; j++) z += (float)qv[j] * sKS[d8 + j];
        }
        sZ[t] = 1.f / (z + 1e-6f);
    }

    // MFMA: each wave does 32 rows x 64 cols
    const int lr = lane & 15;
    const int lq = lane >> 4;
    f32x4 acc[2][4];
    #pragma unroll
    for (int i = 0; i < 2; i++)
        #pragma unroll
        for (int j = 0; j < 4; j++)
            acc[i][j] = (f32x4){0.f, 0.f, 0.f, 0.f};

    bf16x8 af[2][2], bfv[4][2];
    #pragma unroll
    for (int ks = 0; ks < 2; ks++) {
        #pragma unroll
        for (int i = 0; i < 2; i++)
            af[i][ks] = *(const bf16x8*)(&sQ[wv * 32 + i * 16 + lr][lq * 8 + ks * 32]);
        #pragma unroll
        for (int j = 0; j < 4; j++)
            bfv[j][ks] = *(const bf16x8*)(&sKVt[j * 16 + lr][lq * 8 + ks * 32]);
    }
    #pragma unroll
    for (int i = 0; i < 2; i++)
        #pragma unroll
        for (int j = 0; j < 4; j++) {
            acc[i][j] = __builtin_amdgcn_mfma_f32_16x16x32_bf16(af[i][0], bfv[j][0], acc[i][j], 0, 0, 0);
            acc[i][j] = __builtin_amdgcn_mfma_f32_16x16x32_bf16(af[i][1], bfv[j][1], acc[i][j], 0, 0, 0);
        }
    __syncthreads();   // sZ visible to all

    // Epilogue: C/D layout col=lane&15, row=lq*4+reg; scale by sZ[row]
    __hip_bfloat16* op = O + ((size_t)b * SS + s0) * DD + h * HD;
    #pragma unroll
    for (int i = 0; i < 2; i++) {
        #pragma unroll
        for (int j = 0; j < 4; j++) {
            #pragma unroll
            for (int r = 0; r < 4; r++) {
                int row = wv * 32 + i * 16 + lq * 4 + r;
                int col = j * 16 + lr;
                op[(size_t)row * DD + col] = __float2bfloat16(acc[i][j][r] * sZ[row]);
            }
        }
    }
}

// ---------------------------------------------------------------------------
// launch
// ---------------------------------------------------------------------------
extern "C" void kernel_launch(void* const* d_in, const int* in_sizes, int n_in,
                              void* d_out, int out_size, void* d_ws, size_t ws_size,
                              hipStream_t stream) {
    const float* x  = (const float*)d_in[0];
    const float* Wq = (const float*)d_in[1];
    const float* Wk = (const float*)d_in[2];
    const float* Wv = (const float*)d_in[3];
    const float* Wo = (const float*)d_in[4];
    float* out = (float*)d_out;

    // workspace layout (bytes)
    char* ws = (char*)d_ws;
    const size_t XB_BYTES = (size_t)MM * KK * 2;   // 32MB
    const size_t WB_BYTES = (size_t)NN * KK * 2;   // 2MB
    __hip_bfloat16* xb  = (__hip_bfloat16*)(ws);
    __hip_bfloat16* wqb = (__hip_bfloat16*)(ws + XB_BYTES);
    __hip_bfloat16* wkb = (__hip_bfloat16*)(ws + XB_BYTES + WB_BYTES);
    __hip_bfloat16* wvb = (__hip_bfloat16*)(ws + XB_BYTES + 2 * WB_BYTES);
    __hip_bfloat16* wob = (__hip_bfloat16*)(ws + XB_BYTES + 3 * WB_BYTES);
    __hip_bfloat16* qb  = (__hip_bfloat16*)(ws + XB_BYTES + 4 * WB_BYTES);
    __hip_bfloat16* kb  = (__hip_bfloat16*)(ws + 2 * XB_BYTES + 4 * WB_BYTES);
    __hip_bfloat16* vb  = (__hip_bfloat16*)(ws + 3 * XB_BYTES + 4 * WB_BYTES);
    float* KV = (float*)(ws + 4 * XB_BYTES + 4 * WB_BYTES);          // 1MB
    float* KS = (float*)(ws + 4 * XB_BYTES + 4 * WB_BYTES + 1048576); // 16KB
    __hip_bfloat16* ab = xb;  // attn output reuses x's bf16 buffer (x dead by then)

    const int XN = MM * KK;   // 16777216
    const int WN = NN * KK;   // 1048576

    // 1. convert inputs to bf16
    cvt_f32_bf16<<<XN / 4 / 256, 256, 0, stream>>>(x,  xb,  XN / 4);
    cvt_f32_bf16<<<WN / 4 / 256, 256, 0, stream>>>(Wq, wqb, WN / 4);
    cvt_f32_bf16<<<WN / 4 / 256, 256, 0, stream>>>(Wk, wkb, WN / 4);
    cvt_f32_bf16<<<WN / 4 / 256, 256, 0, stream>>>(Wv, wvb, WN / 4);
    cvt_f32_bf16<<<WN / 4 / 256, 256, 0, stream>>>(Wo, wob, WN / 4);

    // 2. projections (elu+1 fused for q,k)
    dim3 ggrid(NN / 128, MM / 128);
    gemm_bt<1><<<ggrid, 256, 0, stream>>>(xb, wqb, qb, nullptr, MM, NN, KK);
    gemm_bt<1><<<ggrid, 256, 0, stream>>>(xb, wkb, kb, nullptr, MM, NN, KK);
    gemm_bt<0><<<ggrid, 256, 0, stream>>>(xb, wvb, vb, nullptr, MM, NN, KK);

    // 3. KV + k_sum (zero accumulators first; ws is poisoned each call)
    hipMemsetAsync(KV, 0, 1048576 + 16384, stream);
    kv_kernel<<<dim3(BB * HH, KV_SPLIT), 256, 0, stream>>>(kb, vb, KV, KS);

    // 4. attention output (normalized), bf16, MFMA
    attn_mfma<<<dim3(BB * HH, SS / 128), 256, 0, stream>>>(qb, KV, KS, ab);

    // 5. final projection -> fp32 d_out
    gemm_bt<2><<<ggrid, 256, 0, stream>>>(ab, wob, nullptr, out, MM, NN, KK);
}

// Round 3
// 440.813 us; speedup vs baseline: 1.2422x; 1.0667x over previous
//
#include <hip/hip_runtime.h>
#include <hip/hip_bf16.h>

// Problem constants (fixed by reference setup_inputs)
#define BB 4
#define SS 4096
#define DD 1024
#define HH 16
#define HD 64
#define MM (BB * SS)      // 16384
#define KK DD             // 1024
#define NN DD             // 1024

typedef __bf16 bf16x8 __attribute__((ext_vector_type(8)));
typedef float f32x4 __attribute__((ext_vector_type(4)));

typedef __attribute__((address_space(3))) void lds_void_t;
typedef const __attribute__((address_space(1))) void glb_void_t;

// ---------------------------------------------------------------------------
// fp32 -> bf16 conversion (vectorized, n must be multiple of 4)
// ---------------------------------------------------------------------------
__global__ __launch_bounds__(256)
void cvt_f32_bf16(const float* __restrict__ in, __hip_bfloat16* __restrict__ out, int n4) {
    int i = blockIdx.x * 256 + threadIdx.x;
    if (i >= n4) return;
    float4 v = ((const float4*)in)[i];
    union { __hip_bfloat16 h[4]; uint2 u; } r;
    r.h[0] = __float2bfloat16(v.x);
    r.h[1] = __float2bfloat16(v.y);
    r.h[2] = __float2bfloat16(v.z);
    r.h[3] = __float2bfloat16(v.w);
    ((uint2*)out)[i] = r.u;
}

// ---------------------------------------------------------------------------
// GEMM: C[M,N] = epilogue( X[M,K] @ W[N,K]^T )   — m97 structure.
// EPI: 0 = store bf16, 1 = elu(x)+1 then bf16, 2 = store fp32
// ---------------------------------------------------------------------------
template<int EPI>
__global__ __launch_bounds__(256)
void gemm_bt(const __hip_bfloat16* __restrict__ X,
             const __hip_bfloat16* __restrict__ W,
             __hip_bfloat16* __restrict__ Cb,
             float* __restrict__ Cf,
             int M, int N, int K)
{
    __shared__ __align__(16) __hip_bfloat16 sA[128][32];
    __shared__ __align__(16) __hip_bfloat16 sB[128][32];

    const int t    = threadIdx.x;
    const int lane = t & 63;
    const int wv   = t >> 6;
    const int wm   = (wv >> 1) * 64;
    const int wn   = (wv & 1) * 64;
    const int m0   = blockIdx.y * 128;
    const int n0   = blockIdx.x * 128;

    const int lrow = lane & 15;
    const int lq   = lane >> 4;

    f32x4 acc[4][4];
    #pragma unroll
    for (int i = 0; i < 4; i++)
        #pragma unroll
        for (int j = 0; j < 4; j++)
            acc[i][j] = (f32x4){0.f, 0.f, 0.f, 0.f};

    for (int kk = 0; kk < K; kk += 32) {
        #pragma unroll
        for (int i = 0; i < 2; i++) {
            int li = (t + i * 256) * 8;
            int r  = li >> 5;
            int c  = li & 31;
            __builtin_amdgcn_global_load_lds(
                (glb_void_t*)&X[(size_t)(m0 + r) * K + kk + c],
                (lds_void_t*)&sA[r][c], 16, 0, 0);
            __builtin_amdgcn_global_load_lds(
                (glb_void_t*)&W[(size_t)(n0 + r) * K + kk + c],
                (lds_void_t*)&sB[r][c], 16, 0, 0);
        }
        __syncthreads();

        bf16x8 af[4], bfv[4];
        #pragma unroll
        for (int i = 0; i < 4; i++) {
            af[i]  = *(const bf16x8*)(&sA[wm + i * 16 + lrow][lq * 8]);
            bfv[i] = *(const bf16x8*)(&sB[wn + i * 16 + lrow][lq * 8]);
        }
        #pragma unroll
        for (int i = 0; i < 4; i++)
            #pragma unroll
            for (int j = 0; j < 4; j++)
                acc[i][j] = __builtin_amdgcn_mfma_f32_16x16x32_bf16(af[i], bfv[j], acc[i][j], 0, 0, 0);
        __syncthreads();
    }

    #pragma unroll
    for (int i = 0; i < 4; i++) {
        #pragma unroll
        for (int j = 0; j < 4; j++) {
            #pragma unroll
            for (int r = 0; r < 4; r++) {
                int row = m0 + wm + i * 16 + lq * 4 + r;
                int col = n0 + wn + j * 16 + lrow;
                float v = acc[i][j][r];
                if (EPI == 1) v = (v > 0.f) ? (v + 1.f) : __expf(v);  // elu(v)+1
                if (EPI == 2) {
                    Cf[(size_t)row * N + col] = v;
                } else {
                    Cb[(size_t)row * N + col] = __float2bfloat16(v);
                }
            }
        }
    }
}

// ---------------------------------------------------------------------------
// KV partials via MFMA: KVp[sp][bh] = sum_{s in chunk} k^T v  (+ k row-sums)
// grid (64 bh, 8 sp), block 256 (4 waves). Each wave owns a 32-s band of each
// 128-s superchunk and a private full 64x64 f32 accumulator; k_sum via
// MFMA against an all-ones B fragment. Cross-wave reduce in LDS, coalesced
// plain stores (NO global atomics). Staging via global_load_lds width-16 with
// XOR-swizzled octet placement so the scalar fragment reads are conflict-free:
//   LDS slot (row r, octet c8) holds global octet (c8 ^ ((r>>3)&3)).
// Output layout: KVp[sp][bh][e][d] (e rows 0..63), row 64 = k_sum[d]. f32.
// ---------------------------------------------------------------------------
#define KV_SPLIT 8
__global__ __launch_bounds__(256)
void kv_mfma(const __hip_bfloat16* __restrict__ Kt,
             const __hip_bfloat16* __restrict__ Vt,
             float* __restrict__ KVp)
{
    __shared__ __hip_bfloat16 sK[128 * 64];
    __shared__ __hip_bfloat16 sV[128 * 64];
    __shared__ float sRed[65 * 66];       // [e][d] padded rows (66) vs banks

    const int bh = blockIdx.x;            // 0..63
    const int b  = bh >> 4;
    const int h  = bh & 15;
    const int sp = blockIdx.y;            // 0..7
    const int t  = threadIdx.x;
    const int lane = t & 63;
    const int wv = t >> 6;
    const int lr = lane & 15;
    const int lq = lane >> 4;
    const int s0blk = sp * (SS / KV_SPLIT);   // 512 rows per block

    const __hip_bfloat16* kbase = Kt + ((size_t)b * SS + s0blk) * DD + h * HD;
    const __hip_bfloat16* vbase = Vt + ((size_t)b * SS + s0blk) * DD + h * HD;

    f32x4 acc[4][4];     // [d-tile][e-tile]
    f32x4 ksacc[4];      // k row sums per d-tile
    #pragma unroll
    for (int i = 0; i < 4; i++) {
        ksacc[i] = (f32x4){0.f, 0.f, 0.f, 0.f};
        #pragma unroll
        for (int j = 0; j < 4; j++)
            acc[i][j] = (f32x4){0.f, 0.f, 0.f, 0.f};
    }

    bf16x8 ones;
    #pragma unroll
    for (int j = 0; j < 8; j++) ones[j] = (__bf16)1.0f;

    for (int sc = 0; sc < 4; sc++) {           // 4 superchunks of 128 rows
        const int srow0 = sc * 128;
        #pragma unroll
        for (int i = 0; i < 4; i++) {
            int slot = i * 256 + t;            // octet slot, 0..1023
            int r = slot >> 3;                 // row 0..127
            int o = (t & 7) ^ ((r >> 3) & 3);  // swizzled global octet
            size_t goff = (size_t)(srow0 + r) * DD + o * 8;
            __builtin_amdgcn_global_load_lds(
                (glb_void_t*)(kbase + goff),
                (lds_void_t*)((char*)sK + slot * 16), 16, 0, 0);
            __builtin_amdgcn_global_load_lds(
                (glb_void_t*)(vbase + goff),
                (lds_void_t*)((char*)sV + slot * 16), 16, 0, 0);
        }
        __syncthreads();

        // wave wv reads its band rows [wv*32, wv*32+32)
        bf16x8 ak[4], bv[4];
        #pragma unroll
        for (int i = 0; i < 4; i++) {
            #pragma unroll
            for (int j = 0; j < 8; j++) {
                int r = wv * 32 + lq * 8 + j;
                int d = i * 16 + lr;
                int idx = r * 64 + (((d >> 3) ^ lq) << 3) + (d & 7);
                ak[i][j] = ((const __bf16*)sK)[idx];
                bv[i][j] = ((const __bf16*)sV)[idx];
            }
        }
        #pragma unroll
        for (int i = 0; i < 4; i++) {
            #pragma unroll
            for (int j = 0; j < 4; j++)
                acc[i][j] = __builtin_amdgcn_mfma_f32_16x16x32_bf16(ak[i], bv[j], acc[i][j], 0, 0, 0);
            ksacc[i] = __builtin_amdgcn_mfma_f32_16x16x32_bf16(ak[i], ones, ksacc[i], 0, 0, 0);
        }
        __syncthreads();
    }

    // Cross-wave reduce in LDS. D layout: row(m=d) = lq*4+reg, col(n=e) = lr.
    // sRed[e][d] (transposed KV): per tile (i,j): e = j*16+lr, d = i*16+lq*4+reg.
    for (int w = 0; w < 4; w++) {
        if (wv == w) {
            #pragma unroll
            for (int i = 0; i < 4; i++) {
                #pragma unroll
                for (int j = 0; j < 4; j++) {
                    float* p = &sRed[(j * 16 + lr) * 66 + i * 16 + lq * 4];
                    if (w == 0) {
                        #pragma unroll
                        for (int r = 0; r < 4; r++) p[r] = acc[i][j][r];
                    } else {
                        #pragma unroll
                        for (int r = 0; r < 4; r++) p[r] += acc[i][j][r];
                    }
                }
                if (lr == 0) {     // k_sum -> row 64 (all cols of ones-MFMA equal)
                    float* p = &sRed[64 * 66 + i * 16 + lq * 4];
                    if (w == 0) {
                        #pragma unroll
                        for (int r = 0; r < 4; r++) p[r] = ksacc[i][r];
                    } else {
                        #pragma unroll
                        for (int r = 0; r < 4; r++) p[r] += ksacc[i][r];
                    }
                }
            }
        }
        __syncthreads();
    }

    // Coalesced store of 65x64 f32 partial
    float* outp = KVp + (size_t)(sp * 64 + bh) * (65 * 64);
    #pragma unroll
    for (int i = 0; i < 17; i++) {
        int idx = i * 256 + t;
        if (idx < 65 * 64) {
            int e = idx >> 6, d = idx & 63;
            outp[idx] = sRed[e * 66 + d];
        }
    }
}

// ---------------------------------------------------------------------------
// Reduce KV_SPLIT partials -> KVt (bf16, [bh][e][d]) + KS (f32, [bh][d])
// grid 64 (one per bh), block 256.
// ---------------------------------------------------------------------------
__global__ __launch_bounds__(256)
void kv_reduce(const float* __restrict__ KVp,
               __hip_bfloat16* __restrict__ KVt,
               float* __restrict__ KS)
{
    const int bh = blockIdx.x;
    const int t  = threadIdx.x;
    #pragma unroll
    for (int i = 0; i < 16; i++) {
        int idx = i * 256 + t;                 // e*64+d
        float s = 0.f;
        #pragma unroll
        for (int sp = 0; sp < KV_SPLIT; sp++)
            s += KVp[((size_t)(sp * 64 + bh) * 65) * 64 + idx];
        KVt[(size_t)bh * 4096 + idx] = __float2bfloat16(s);
    }
    if (t < 64) {
        float s = 0.f;
        #pragma unroll
        for (int sp = 0; sp < KV_SPLIT; sp++)
            s += KVp[((size_t)(sp * 64 + bh) * 65 + 64) * 64 + t];
        KS[bh * 64 + t] = s;
    }
}

// ---------------------------------------------------------------------------
// MFMA attention apply: out[b,s,h,:] = (q[b,s,h,:] @ KV[b,h]) / (q.KS + eps)
// KVt comes pre-transposed ([e][d], bf16) -> plain vector copy into LDS.
// ---------------------------------------------------------------------------
__global__ __launch_bounds__(256)
void attn_mfma(const __hip_bfloat16* __restrict__ Q,
               const __hip_bfloat16* __restrict__ KVt,
               const float* __restrict__ KS,
               __hip_bfloat16* __restrict__ O)
{
    const int bh = blockIdx.x;       // 0..63
    const int b  = bh >> 4;
    const int h  = bh & 15;
    const int s0 = blockIdx.y * 128;
    const int t  = threadIdx.x;
    const int lane = t & 63;
    const int wv = t >> 6;

    __shared__ __align__(16) __hip_bfloat16 sQ[128][72];
    __shared__ __align__(16) __hip_bfloat16 sKVt[64][72];   // [e][d]
    __shared__ float sKS[64];
    __shared__ float sZ[128];

    // KVt: 8KB bf16, direct vector copy (512 16B chunks)
    {
        const float4* kvp = (const float4*)(KVt + (size_t)bh * 4096);
        #pragma unroll
        for (int i = 0; i < 2; i++) {
            int c = i * 256 + t;       // 16B chunk id, 0..511
            *(float4*)(&sKVt[c >> 3][(c & 7) * 8]) = kvp[c];
        }
        if (t < 64) sKS[t] = KS[bh * 64 + t];
    }
    // Q tile: rows s0..s0+127, cols h*64..h*64+63
    {
        const __hip_bfloat16* qp = Q + ((size_t)b * SS + s0) * DD + h * HD;
        int r  = t >> 1;
        int c0 = (t & 1) * 32;
        #pragma unroll
        for (int i = 0; i < 32; i += 8)
            *(float4*)(&sQ[r][c0 + i]) = *(const float4*)(qp + (size_t)r * DD + c0 + i);
    }
    __syncthreads();

    if (t < 128) {
        float z = 0.f;
        #pragma unroll
        for (int d8 = 0; d8 < 64; d8 += 8) {
            bf16x8 qv = *(const bf16x8*)(&sQ[t][d8]);
            #pragma unroll
            for (int j = 0; j < 8; j++) z += (float)qv[j] * sKS[d8 + j];
        }
        sZ[t] = 1.f / (z + 1e-6f);
    }

    const int lr = lane & 15;
    const int lq = lane >> 4;
    f32x4 acc[2][4];
    #pragma unroll
    for (int i = 0; i < 2; i++)
        #pragma unroll
        for (int j = 0; j < 4; j++)
            acc[i][j] = (f32x4){0.f, 0.f, 0.f, 0.f};

    bf16x8 af[2][2], bfv[4][2];
    #pragma unroll
    for (int ks = 0; ks < 2; ks++) {
        #pragma unroll
        for (int i = 0; i < 2; i++)
            af[i][ks] = *(const bf16x8*)(&sQ[wv * 32 + i * 16 + lr][lq * 8 + ks * 32]);
        #pragma unroll
        for (int j = 0; j < 4; j++)
            bfv[j][ks] = *(const bf16x8*)(&sKVt[j * 16 + lr][lq * 8 + ks * 32]);
    }
    #pragma unroll
    for (int i = 0; i < 2; i++)
        #pragma unroll
        for (int j = 0; j < 4; j++) {
            acc[i][j] = __builtin_amdgcn_mfma_f32_16x16x32_bf16(af[i][0], bfv[j][0], acc[i][j], 0, 0, 0);
            acc[i][j] = __builtin_amdgcn_mfma_f32_16x16x32_bf16(af[i][1], bfv[j][1], acc[i][j], 0, 0, 0);
        }
    __syncthreads();

    __hip_bfloat16* op = O + ((size_t)b * SS + s0) * DD + h * HD;
    #pragma unroll
    for (int i = 0; i < 2; i++) {
        #pragma unroll
        for (int j = 0; j < 4; j++) {
            #pragma unroll
            for (int r = 0; r < 4; r++) {
                int row = wv * 32 + i * 16 + lq * 4 + r;
                int col = j * 16 + lr;
                op[(size_t)row * DD + col] = __float2bfloat16(acc[i][j][r] * sZ[row]);
            }
        }
    }
}

// ---------------------------------------------------------------------------
// launch
// ---------------------------------------------------------------------------
extern "C" void kernel_launch(void* const* d_in, const int* in_sizes, int n_in,
                              void* d_out, int out_size, void* d_ws, size_t ws_size,
                              hipStream_t stream) {
    const float* x  = (const float*)d_in[0];
    const float* Wq = (const float*)d_in[1];
    const float* Wk = (const float*)d_in[2];
    const float* Wv = (const float*)d_in[3];
    const float* Wo = (const float*)d_in[4];
    float* out = (float*)d_out;

    // workspace layout (bytes)
    char* ws = (char*)d_ws;
    const size_t XB_BYTES = (size_t)MM * KK * 2;   // 32MB
    const size_t WB_BYTES = (size_t)NN * KK * 2;   // 2MB
    __hip_bfloat16* xb  = (__hip_bfloat16*)(ws);
    __hip_bfloat16* wqb = (__hip_bfloat16*)(ws + XB_BYTES);
    __hip_bfloat16* wkb = (__hip_bfloat16*)(ws + XB_BYTES + WB_BYTES);
    __hip_bfloat16* wvb = (__hip_bfloat16*)(ws + XB_BYTES + 2 * WB_BYTES);
    __hip_bfloat16* wob = (__hip_bfloat16*)(ws + XB_BYTES + 3 * WB_BYTES);
    __hip_bfloat16* qb  = (__hip_bfloat16*)(ws + XB_BYTES + 4 * WB_BYTES);
    __hip_bfloat16* kb  = (__hip_bfloat16*)(ws + 2 * XB_BYTES + 4 * WB_BYTES);
    __hip_bfloat16* vb  = (__hip_bfloat16*)(ws + 3 * XB_BYTES + 4 * WB_BYTES);
    __hip_bfloat16* KVt = (__hip_bfloat16*)(ws + 4 * XB_BYTES + 4 * WB_BYTES);          // 512KB
    float*          KS  = (float*)(ws + 4 * XB_BYTES + 4 * WB_BYTES + 524288);          // 16KB
    // KV partials (8.3MB f32) OVERLAY the xb region: xb (bf16 x) is dead after
    // the 3 QKV GEMMs; kv_mfma writes KVp, kv_reduce consumes it, THEN
    // attn_mfma writes ab (= xb) over it. Stream-ordered, safe.
    float* KVp = (float*)(ws);
    __hip_bfloat16* ab = xb;   // attn output reuses x's bf16 buffer

    const int XN = MM * KK;   // 16777216
    const int WN = NN * KK;   // 1048576

    // 1. convert inputs to bf16
    cvt_f32_bf16<<<XN / 4 / 256, 256, 0, stream>>>(x,  xb,  XN / 4);
    cvt_f32_bf16<<<WN / 4 / 256, 256, 0, stream>>>(Wq, wqb, WN / 4);
    cvt_f32_bf16<<<WN / 4 / 256, 256, 0, stream>>>(Wk, wkb, WN / 4);
    cvt_f32_bf16<<<WN / 4 / 256, 256, 0, stream>>>(Wv, wvb, WN / 4);
    cvt_f32_bf16<<<WN / 4 / 256, 256, 0, stream>>>(Wo, wob, WN / 4);

    // 2. projections (elu+1 fused for q,k)
    dim3 ggrid(NN / 128, MM / 128);
    gemm_bt<1><<<ggrid, 256, 0, stream>>>(xb, wqb, qb, nullptr, MM, NN, KK);
    gemm_bt<1><<<ggrid, 256, 0, stream>>>(xb, wkb, kb, nullptr, MM, NN, KK);
    gemm_bt<0><<<ggrid, 256, 0, stream>>>(xb, wvb, vb, nullptr, MM, NN, KK);

    // 3. KV + k_sum partials (MFMA, no atomics), then reduce
    kv_mfma<<<dim3(BB * HH, KV_SPLIT), 256, 0, stream>>>(kb, vb, KVp);
    kv_reduce<<<BB * HH, 256, 0, stream>>>(KVp, KVt, KS);

    // 4. attention output (normalized), bf16, MFMA
    attn_mfma<<<dim3(BB * HH, SS / 128), 256, 0, stream>>>(qb, KVt, KS, ab);

    // 5. final projection -> fp32 d_out
    gemm_bt<2><<<ggrid, 256, 0, stream>>>(ab, wob, nullptr, out, MM, NN, KK);
}

// Round 4
// 375.280 us; speedup vs baseline: 1.4592x; 1.1746x over previous
//
#include <hip/hip_runtime.h>
#include <hip/hip_bf16.h>

// Problem constants (fixed by reference setup_inputs)
#define BB 4
#define SS 4096
#define DD 1024
#define HH 16
#define HD 64
#define MM (BB * SS)      // 16384
#define KK DD             // 1024
#define NN DD             // 1024

typedef __bf16 bf16x8 __attribute__((ext_vector_type(8)));
typedef float f32x4 __attribute__((ext_vector_type(4)));

typedef __attribute__((address_space(3))) void lds_void_t;
typedef const __attribute__((address_space(1))) void glb_void_t;

// ---------------------------------------------------------------------------
// fp32 -> bf16 conversion (vectorized)
// ---------------------------------------------------------------------------
__global__ __launch_bounds__(256)
void cvt_f32_bf16(const float* __restrict__ in, __hip_bfloat16* __restrict__ out, int n4) {
    int i = blockIdx.x * 256 + threadIdx.x;
    if (i >= n4) return;
    float4 v = ((const float4*)in)[i];
    union { __hip_bfloat16 h[4]; uint2 u; } r;
    r.h[0] = __float2bfloat16(v.x);
    r.h[1] = __float2bfloat16(v.y);
    r.h[2] = __float2bfloat16(v.z);
    r.h[3] = __float2bfloat16(v.w);
    ((uint2*)out)[i] = r.u;
}

// ---------------------------------------------------------------------------
// Fused QKV GEMM: {Q,K,V}[M,N] = elu?( X[M,K] @ W{q,k,v}[N,K]^T )
// Per block: 128m x 64n per weight. 4 waves, wave = 64m x 32n per weight.
// One A-tile staged per K-iter serves 3 B-tiles -> 24 MFMA : 5 vmem loads.
// Block swizzle: linear id -> chunk of 32m x 8n; n == XCD (ids mod 8) so
// each XCD pins its B columns in L2 while the shared A band is L3-resident.
// grid = 2048 (128m x 16n), 1D.
// ---------------------------------------------------------------------------
__global__ __launch_bounds__(256, 2)
void gemm_qkv(const __hip_bfloat16* __restrict__ X,
              const __hip_bfloat16* __restrict__ Wq,
              const __hip_bfloat16* __restrict__ Wk,
              const __hip_bfloat16* __restrict__ Wv,
              __hip_bfloat16* __restrict__ Qo,
              __hip_bfloat16* __restrict__ Ko,
              __hip_bfloat16* __restrict__ Vo)
{
    __shared__ __align__(16) __hip_bfloat16 sA[128][32];
    __shared__ __align__(16) __hip_bfloat16 sBq[64][32];
    __shared__ __align__(16) __hip_bfloat16 sBk[64][32];
    __shared__ __align__(16) __hip_bfloat16 sBv[64][32];

    const int l     = blockIdx.x;          // 0..2047
    const int chunk = l >> 8;              // 0..7  (32m x 8n regions)
    const int idx   = l & 255;
    const int n0 = ((chunk & 1) * 8 + (idx & 7)) * 64;     // 0..960
    const int m0 = ((chunk >> 1) * 32 + (idx >> 3)) * 128; // 0..16256

    const int t    = threadIdx.x;
    const int lane = t & 63;
    const int wv   = t >> 6;
    const int wm   = (wv >> 1) * 64;       // 0 or 64
    const int wn   = (wv & 1) * 32;        // 0 or 32
    const int lr   = lane & 15;
    const int lq   = lane >> 4;

    f32x4 aq[4][2], ak[4][2], av[4][2];
    #pragma unroll
    for (int i = 0; i < 4; i++)
        #pragma unroll
        for (int j = 0; j < 2; j++) {
            aq[i][j] = (f32x4){0.f, 0.f, 0.f, 0.f};
            ak[i][j] = (f32x4){0.f, 0.f, 0.f, 0.f};
            av[i][j] = (f32x4){0.f, 0.f, 0.f, 0.f};
        }

    for (int kk = 0; kk < KK; kk += 32) {
        // A: 512 slots of 16B -> 2 per thread
        #pragma unroll
        for (int i = 0; i < 2; i++) {
            int s = i * 256 + t;
            int r = s >> 2, c = (s & 3) * 8;
            __builtin_amdgcn_global_load_lds(
                (glb_void_t*)&X[(size_t)(m0 + r) * KK + kk + c],
                (lds_void_t*)&sA[r][c], 16, 0, 0);
        }
        // B tiles: 256 slots each -> 1 per thread per weight
        {
            int r = t >> 2, c = (t & 3) * 8;
            size_t go = (size_t)(n0 + r) * KK + kk + c;
            __builtin_amdgcn_global_load_lds((glb_void_t*)&Wq[go], (lds_void_t*)&sBq[r][c], 16, 0, 0);
            __builtin_amdgcn_global_load_lds((glb_void_t*)&Wk[go], (lds_void_t*)&sBk[r][c], 16, 0, 0);
            __builtin_amdgcn_global_load_lds((glb_void_t*)&Wv[go], (lds_void_t*)&sBv[r][c], 16, 0, 0);
        }
        __syncthreads();

        bf16x8 af[4], bq[2], bk[2], bv[2];
        #pragma unroll
        for (int i = 0; i < 4; i++)
            af[i] = *(const bf16x8*)(&sA[wm + i * 16 + lr][lq * 8]);
        #pragma unroll
        for (int j = 0; j < 2; j++) {
            bq[j] = *(const bf16x8*)(&sBq[wn + j * 16 + lr][lq * 8]);
            bk[j] = *(const bf16x8*)(&sBk[wn + j * 16 + lr][lq * 8]);
            bv[j] = *(const bf16x8*)(&sBv[wn + j * 16 + lr][lq * 8]);
        }
        #pragma unroll
        for (int i = 0; i < 4; i++)
            #pragma unroll
            for (int j = 0; j < 2; j++) {
                aq[i][j] = __builtin_amdgcn_mfma_f32_16x16x32_bf16(af[i], bq[j], aq[i][j], 0, 0, 0);
                ak[i][j] = __builtin_amdgcn_mfma_f32_16x16x32_bf16(af[i], bk[j], ak[i][j], 0, 0, 0);
                av[i][j] = __builtin_amdgcn_mfma_f32_16x16x32_bf16(af[i], bv[j], av[i][j], 0, 0, 0);
            }
        __syncthreads();
    }

    // Epilogue: C/D layout col=lane&15, row=(lane>>4)*4+reg
    #pragma unroll
    for (int i = 0; i < 4; i++) {
        #pragma unroll
        for (int j = 0; j < 2; j++) {
            #pragma unroll
            for (int r = 0; r < 4; r++) {
                size_t off = (size_t)(m0 + wm + i * 16 + lq * 4 + r) * NN
                           + (n0 + wn + j * 16 + lr);
                float vq = aq[i][j][r];
                float vk = ak[i][j][r];
                Qo[off] = __float2bfloat16(vq > 0.f ? vq + 1.f : __expf(vq));
                Ko[off] = __float2bfloat16(vk > 0.f ? vk + 1.f : __expf(vk));
                Vo[off] = __float2bfloat16(av[i][j][r]);
            }
        }
    }
}

// ---------------------------------------------------------------------------
// Output GEMM: C[M,N](f32) = A[M,K] @ W[N,K]^T, 128x128 tile, m97 staging.
// Block swizzle: 32m x 8n chunks, n == id mod 8 (XCD pinning).
// grid = 1024 (128m x 8n), 1D.
// ---------------------------------------------------------------------------
__global__ __launch_bounds__(256)
void gemm_out(const __hip_bfloat16* __restrict__ X,
              const __hip_bfloat16* __restrict__ W,
              float* __restrict__ Cf)
{
    __shared__ __align__(16) __hip_bfloat16 sA[128][32];
    __shared__ __align__(16) __hip_bfloat16 sB[128][32];

    const int l     = blockIdx.x;          // 0..1023
    const int chunk = l >> 8;              // 0..3
    const int n0 = (l & 7) * 128;
    const int m0 = (chunk * 32 + ((l >> 3) & 31)) * 128;

    const int t    = threadIdx.x;
    const int lane = t & 63;
    const int wv   = t >> 6;
    const int wm   = (wv >> 1) * 64;
    const int wn   = (wv & 1) * 64;
    const int lrow = lane & 15;
    const int lq   = lane >> 4;

    f32x4 acc[4][4];
    #pragma unroll
    for (int i = 0; i < 4; i++)
        #pragma unroll
        for (int j = 0; j < 4; j++)
            acc[i][j] = (f32x4){0.f, 0.f, 0.f, 0.f};

    for (int kk = 0; kk < KK; kk += 32) {
        #pragma unroll
        for (int i = 0; i < 2; i++) {
            int li = (t + i * 256) * 8;
            int r  = li >> 5;
            int c  = li & 31;
            __builtin_amdgcn_global_load_lds(
                (glb_void_t*)&X[(size_t)(m0 + r) * KK + kk + c],
                (lds_void_t*)&sA[r][c], 16, 0, 0);
            __builtin_amdgcn_global_load_lds(
                (glb_void_t*)&W[(size_t)(n0 + r) * KK + kk + c],
                (lds_void_t*)&sB[r][c], 16, 0, 0);
        }
        __syncthreads();

        bf16x8 af[4], bfv[4];
        #pragma unroll
        for (int i = 0; i < 4; i++) {
            af[i]  = *(const bf16x8*)(&sA[wm + i * 16 + lrow][lq * 8]);
            bfv[i] = *(const bf16x8*)(&sB[wn + i * 16 + lrow][lq * 8]);
        }
        #pragma unroll
        for (int i = 0; i < 4; i++)
            #pragma unroll
            for (int j = 0; j < 4; j++)
                acc[i][j] = __builtin_amdgcn_mfma_f32_16x16x32_bf16(af[i], bfv[j], acc[i][j], 0, 0, 0);
        __syncthreads();
    }

    #pragma unroll
    for (int i = 0; i < 4; i++)
        #pragma unroll
        for (int j = 0; j < 4; j++)
            #pragma unroll
            for (int r = 0; r < 4; r++) {
                int row = m0 + wm + i * 16 + lq * 4 + r;
                int col = n0 + wn + j * 16 + lrow;
                Cf[(size_t)row * NN + col] = acc[i][j][r];
            }
}

// ---------------------------------------------------------------------------
// KV partials via MFMA (unchanged from R3 — verified)
// ---------------------------------------------------------------------------
#define KV_SPLIT 8
__global__ __launch_bounds__(256)
void kv_mfma(const __hip_bfloat16* __restrict__ Kt,
             const __hip_bfloat16* __restrict__ Vt,
             float* __restrict__ KVp)
{
    __shared__ __hip_bfloat16 sK[128 * 64];
    __shared__ __hip_bfloat16 sV[128 * 64];
    __shared__ float sRed[65 * 66];

    const int bh = blockIdx.x;
    const int b  = bh >> 4;
    const int h  = bh & 15;
    const int sp = blockIdx.y;
    const int t  = threadIdx.x;
    const int lane = t & 63;
    const int wv = t >> 6;
    const int lr = lane & 15;
    const int lq = lane >> 4;
    const int s0blk = sp * (SS / KV_SPLIT);

    const __hip_bfloat16* kbase = Kt + ((size_t)b * SS + s0blk) * DD + h * HD;
    const __hip_bfloat16* vbase = Vt + ((size_t)b * SS + s0blk) * DD + h * HD;

    f32x4 acc[4][4];
    f32x4 ksacc[4];
    #pragma unroll
    for (int i = 0; i < 4; i++) {
        ksacc[i] = (f32x4){0.f, 0.f, 0.f, 0.f};
        #pragma unroll
        for (int j = 0; j < 4; j++)
            acc[i][j] = (f32x4){0.f, 0.f, 0.f, 0.f};
    }

    bf16x8 ones;
    #pragma unroll
    for (int j = 0; j < 8; j++) ones[j] = (__bf16)1.0f;

    for (int sc = 0; sc < 4; sc++) {
        const int srow0 = sc * 128;
        #pragma unroll
        for (int i = 0; i < 4; i++) {
            int slot = i * 256 + t;
            int r = slot >> 3;
            int o = (t & 7) ^ ((r >> 3) & 3);
            size_t goff = (size_t)(srow0 + r) * DD + o * 8;
            __builtin_amdgcn_global_load_lds(
                (glb_void_t*)(kbase + goff),
                (lds_void_t*)((char*)sK + slot * 16), 16, 0, 0);
            __builtin_amdgcn_global_load_lds(
                (glb_void_t*)(vbase + goff),
                (lds_void_t*)((char*)sV + slot * 16), 16, 0, 0);
        }
        __syncthreads();

        bf16x8 ak[4], bv[4];
        #pragma unroll
        for (int i = 0; i < 4; i++) {
            #pragma unroll
            for (int j = 0; j < 8; j++) {
                int r = wv * 32 + lq * 8 + j;
                int d = i * 16 + lr;
                int idx = r * 64 + (((d >> 3) ^ lq) << 3) + (d & 7);
                ak[i][j] = ((const __bf16*)sK)[idx];
                bv[i][j] = ((const __bf16*)sV)[idx];
            }
        }
        #pragma unroll
        for (int i = 0; i < 4; i++) {
            #pragma unroll
            for (int j = 0; j < 4; j++)
                acc[i][j] = __builtin_amdgcn_mfma_f32_16x16x32_bf16(ak[i], bv[j], acc[i][j], 0, 0, 0);
            ksacc[i] = __builtin_amdgcn_mfma_f32_16x16x32_bf16(ak[i], ones, ksacc[i], 0, 0, 0);
        }
        __syncthreads();
    }

    for (int w = 0; w < 4; w++) {
        if (wv == w) {
            #pragma unroll
            for (int i = 0; i < 4; i++) {
                #pragma unroll
                for (int j = 0; j < 4; j++) {
                    float* p = &sRed[(j * 16 + lr) * 66 + i * 16 + lq * 4];
                    if (w == 0) {
                        #pragma unroll
                        for (int r = 0; r < 4; r++) p[r] = acc[i][j][r];
                    } else {
                        #pragma unroll
                        for (int r = 0; r < 4; r++) p[r] += acc[i][j][r];
                    }
                }
                if (lr == 0) {
                    float* p = &sRed[64 * 66 + i * 16 + lq * 4];
                    if (w == 0) {
                        #pragma unroll
                        for (int r = 0; r < 4; r++) p[r] = ksacc[i][r];
                    } else {
                        #pragma unroll
                        for (int r = 0; r < 4; r++) p[r] += ksacc[i][r];
                    }
                }
            }
        }
        __syncthreads();
    }

    float* outp = KVp + (size_t)(sp * 64 + bh) * (65 * 64);
    #pragma unroll
    for (int i = 0; i < 17; i++) {
        int idx = i * 256 + t;
        if (idx < 65 * 64) {
            int e = idx >> 6, d = idx & 63;
            outp[idx] = sRed[e * 66 + d];
        }
    }
}

// ---------------------------------------------------------------------------
// Reduce partials -> KVt (bf16 [bh][e][d]) + KS (f32) (unchanged)
// ---------------------------------------------------------------------------
__global__ __launch_bounds__(256)
void kv_reduce(const float* __restrict__ KVp,
               __hip_bfloat16* __restrict__ KVt,
               float* __restrict__ KS)
{
    const int bh = blockIdx.x;
    const int t  = threadIdx.x;
    #pragma unroll
    for (int i = 0; i < 16; i++) {
        int idx = i * 256 + t;
        float s = 0.f;
        #pragma unroll
        for (int sp = 0; sp < KV_SPLIT; sp++)
            s += KVp[((size_t)(sp * 64 + bh) * 65) * 64 + idx];
        KVt[(size_t)bh * 4096 + idx] = __float2bfloat16(s);
    }
    if (t < 64) {
        float s = 0.f;
        #pragma unroll
        for (int sp = 0; sp < KV_SPLIT; sp++)
            s += KVp[((size_t)(sp * 64 + bh) * 65 + 64) * 64 + t];
        KS[bh * 64 + t] = s;
    }
}

// ---------------------------------------------------------------------------
// MFMA attention apply (unchanged from R3 — verified)
// ---------------------------------------------------------------------------
__global__ __launch_bounds__(256)
void attn_mfma(const __hip_bfloat16* __restrict__ Q,
               const __hip_bfloat16* __restrict__ KVt,
               const float* __restrict__ KS,
               __hip_bfloat16* __restrict__ O)
{
    const int bh = blockIdx.x;
    const int b  = bh >> 4;
    const int h  = bh & 15;
    const int s0 = blockIdx.y * 128;
    const int t  = threadIdx.x;
    const int lane = t & 63;
    const int wv = t >> 6;

    __shared__ __align__(16) __hip_bfloat16 sQ[128][72];
    __shared__ __align__(16) __hip_bfloat16 sKVt[64][72];
    __shared__ float sKS[64];
    __shared__ float sZ[128];

    {
        const float4* kvp = (const float4*)(KVt + (size_t)bh * 4096);
        #pragma unroll
        for (int i = 0; i < 2; i++) {
            int c = i * 256 + t;
            *(float4*)(&sKVt[c >> 3][(c & 7) * 8]) = kvp[c];
        }
        if (t < 64) sKS[t] = KS[bh * 64 + t];
    }
    {
        const __hip_bfloat16* qp = Q + ((size_t)b * SS + s0) * DD + h * HD;
        int r  = t >> 1;
        int c0 = (t & 1) * 32;
        #pragma unroll
        for (int i = 0; i < 32; i += 8)
            *(float4*)(&sQ[r][c0 + i]) = *(const float4*)(qp + (size_t)r * DD + c0 + i);
    }
    __syncthreads();

    if (t < 128) {
        float z = 0.f;
        #pragma unroll
        for (int d8 = 0; d8 < 64; d8 += 8) {
            bf16x8 qv = *(const bf16x8*)(&sQ[t][d8]);
            #pragma unroll
            for (int j = 0; j < 8; j++) z += (float)qv[j] * sKS[d8 + j];
        }
        sZ[t] = 1.f / (z + 1e-6f);
    }

    const int lr = lane & 15;
    const int lq = lane >> 4;
    f32x4 acc[2][4];
    #pragma unroll
    for (int i = 0; i < 2; i++)
        #pragma unroll
        for (int j = 0; j < 4; j++)
            acc[i][j] = (f32x4){0.f, 0.f, 0.f, 0.f};

    bf16x8 af[2][2], bfv[4][2];
    #pragma unroll
    for (int ks = 0; ks < 2; ks++) {
        #pragma unroll
        for (int i = 0; i < 2; i++)
            af[i][ks] = *(const bf16x8*)(&sQ[wv * 32 + i * 16 + lr][lq * 8 + ks * 32]);
        #pragma unroll
        for (int j = 0; j < 4; j++)
            bfv[j][ks] = *(const bf16x8*)(&sKVt[j * 16 + lr][lq * 8 + ks * 32]);
    }
    #pragma unroll
    for (int i = 0; i < 2; i++)
        #pragma unroll
        for (int j = 0; j < 4; j++) {
            acc[i][j] = __builtin_amdgcn_mfma_f32_16x16x32_bf16(af[i][0], bfv[j][0], acc[i][j], 0, 0, 0);
            acc[i][j] = __builtin_amdgcn_mfma_f32_16x16x32_bf16(af[i][1], bfv[j][1], acc[i][j], 0, 0, 0);
        }
    __syncthreads();

    __hip_bfloat16* op = O + ((size_t)b * SS + s0) * DD + h * HD;
    #pragma unroll
    for (int i = 0; i < 2; i++)
        #pragma unroll
        for (int j = 0; j < 4; j++)
            #pragma unroll
            for (int r = 0; r < 4; r++) {
                int row = wv * 32 + i * 16 + lq * 4 + r;
                int col = j * 16 + lr;
                op[(size_t)row * DD + col] = __float2bfloat16(acc[i][j][r] * sZ[row]);
            }
}

// ---------------------------------------------------------------------------
// launch
// ---------------------------------------------------------------------------
extern "C" void kernel_launch(void* const* d_in, const int* in_sizes, int n_in,
                              void* d_out, int out_size, void* d_ws, size_t ws_size,
                              hipStream_t stream) {
    const float* x  = (const float*)d_in[0];
    const float* Wq = (const float*)d_in[1];
    const float* Wk = (const float*)d_in[2];
    const float* Wv = (const float*)d_in[3];
    const float* Wo = (const float*)d_in[4];
    float* out = (float*)d_out;

    char* ws = (char*)d_ws;
    const size_t XB_BYTES = (size_t)MM * KK * 2;   // 32MB
    const size_t WB_BYTES = (size_t)NN * KK * 2;   // 2MB
    __hip_bfloat16* xb  = (__hip_bfloat16*)(ws);
    __hip_bfloat16* wqb = (__hip_bfloat16*)(ws + XB_BYTES);
    __hip_bfloat16* wkb = (__hip_bfloat16*)(ws + XB_BYTES + WB_BYTES);
    __hip_bfloat16* wvb = (__hip_bfloat16*)(ws + XB_BYTES + 2 * WB_BYTES);
    __hip_bfloat16* wob = (__hip_bfloat16*)(ws + XB_BYTES + 3 * WB_BYTES);
    __hip_bfloat16* qb  = (__hip_bfloat16*)(ws + XB_BYTES + 4 * WB_BYTES);
    __hip_bfloat16* kb  = (__hip_bfloat16*)(ws + 2 * XB_BYTES + 4 * WB_BYTES);
    __hip_bfloat16* vb  = (__hip_bfloat16*)(ws + 3 * XB_BYTES + 4 * WB_BYTES);
    __hip_bfloat16* KVt = (__hip_bfloat16*)(ws + 4 * XB_BYTES + 4 * WB_BYTES);          // 512KB
    float*          KS  = (float*)(ws + 4 * XB_BYTES + 4 * WB_BYTES + 524288);          // 16KB
    // KV partials (8.3MB f32) overlay xb (dead after QKV GEMM; attn writes
    // ab=xb only after kv_reduce). Stream-ordered, safe.
    float* KVp = (float*)(ws);
    __hip_bfloat16* ab = xb;

    const int XN = MM * KK;
    const int WN = NN * KK;

    // 1. convert inputs to bf16
    cvt_f32_bf16<<<XN / 4 / 256, 256, 0, stream>>>(x,  xb,  XN / 4);
    cvt_f32_bf16<<<WN / 4 / 256, 256, 0, stream>>>(Wq, wqb, WN / 4);
    cvt_f32_bf16<<<WN / 4 / 256, 256, 0, stream>>>(Wk, wkb, WN / 4);
    cvt_f32_bf16<<<WN / 4 / 256, 256, 0, stream>>>(Wv, wvb, WN / 4);
    cvt_f32_bf16<<<WN / 4 / 256, 256, 0, stream>>>(Wo, wob, WN / 4);

    // 2. fused QKV projection (elu+1 fused for q,k)
    gemm_qkv<<<2048, 256, 0, stream>>>(xb, wqb, wkb, wvb, qb, kb, vb);

    // 3. KV + k_sum partials (MFMA, no atomics), then reduce
    kv_mfma<<<dim3(BB * HH, KV_SPLIT), 256, 0, stream>>>(kb, vb, KVp);
    kv_reduce<<<BB * HH, 256, 0, stream>>>(KVp, KVt, KS);

    // 4. attention output (normalized), bf16, MFMA
    attn_mfma<<<dim3(BB * HH, SS / 128), 256, 0, stream>>>(qb, KVt, KS, ab);

    // 5. final projection -> fp32 d_out
    gemm_out<<<1024, 256, 0, stream>>>(ab, wob, out);
}